// Round 6
// baseline (5203.669 us; speedup 1.0000x reference)
//
#include <hip/hip_runtime.h>

#define N_NODES 50000
#define N_EDGES 800000
#define D 128
#define ED 64
#define NLAYERS 3

// ---------------- prep kernels (build dst-sorted CSR each call) ----------------

__global__ void hist_kernel(const int* __restrict__ dst, int* __restrict__ deg) {
    int e = blockIdx.x * blockDim.x + threadIdx.x;
    if (e < N_EDGES) atomicAdd(&deg[dst[e]], 1);
}

__global__ void scan_kernel(int* __restrict__ deg_cursor, int* __restrict__ row_start) {
    __shared__ int part[1024];
    const int t = threadIdx.x;
    const int CH = (N_NODES + 1023) / 1024;  // 49
    int a = t * CH;
    int b = min(a + CH, N_NODES);
    int s = 0;
    for (int i = a; i < b; ++i) s += deg_cursor[i];
    part[t] = s;
    __syncthreads();
    for (int off = 1; off < 1024; off <<= 1) {
        int v = (t >= off) ? part[t - off] : 0;
        __syncthreads();
        part[t] += v;
        __syncthreads();
    }
    int base = (t == 0) ? 0 : part[t - 1];
    for (int i = a; i < b; ++i) {
        int d = deg_cursor[i];
        row_start[i] = base;
        deg_cursor[i] = base;
        base += d;
    }
    if (t == 1023) row_start[N_NODES] = part[1023];
}

__global__ void scatter_kernel(const int* __restrict__ dst, int* __restrict__ cursor,
                               int* __restrict__ perm) {
    int e = blockIdx.x * blockDim.x + threadIdx.x;
    if (e < N_EDGES) {
        int pos = atomicAdd(&cursor[dst[e]], 1);
        perm[pos] = e;
    }
}

// physically reorder edge_attr/src into dst-sorted order (once per call).
__global__ void reorder_kernel(const float4* __restrict__ ea, const int* __restrict__ perm,
                               const int* __restrict__ src,
                               float4* __restrict__ ea_d, int* __restrict__ srcd) {
    int idx = blockIdx.x * blockDim.x + threadIdx.x;
    int i = idx >> 2, q = idx & 3;
    if (i < N_EDGES) {
        int pe = perm[i];
        const float4* srow = ea + (size_t)pe * (ED / 4);
        float4* drow = ea_d + (size_t)i * (ED / 4);
        #pragma unroll
        for (int j = 0; j < 4; ++j) drow[q * 4 + j] = srow[q * 4 + j];
        if (q == 0) srcd[i] = src[pe];
    }
}

// ---------------- edge pass: per-wave segmented streaming ----------------
// 1 output column per lane; We column held in 64 VGPRs (under the 128-reg cap
// of (256,4) -> no demotion to loads, the r5 failure mode). Two waves per
// edge-range (column halves). ea row via wave-uniform float4 broadcasts
// (L3-resident stream); x[src] one coalesced 256 B gather per edge per wave.

__global__ __launch_bounds__(256, 4)
void edge_agg_kernel(const float* __restrict__ x,
                     const float* __restrict__ eaA,   // [E][ED] (dst-sorted if direct)
                     const int* __restrict__ srcA,
                     const int* __restrict__ permN,   // nullptr => direct (sorted) mode
                     const int* __restrict__ row_start,
                     const float* __restrict__ We,    // [ED][D]
                     const float* __restrict__ be,    // [D]
                     float* __restrict__ hpre,        // [N][D]
                     int nwaves, int epw)
{
    const int t    = threadIdx.x;
    const int lane = t & 63;
    const int gw   = (blockIdx.x * 256 + t) >> 6;
    if (gw >= nwaves) return;
    const int rid  = gw >> 1;          // edge-range id
    const int half = gw & 1;           // column half
    const int c    = half * 64 + lane; // owned output column
    const int nranges = nwaves >> 1;

    // We column c in 64 VGPRs (statically indexed after full unroll)
    float wk[64];
    #pragma unroll
    for (int k = 0; k < 64; ++k) wk[k] = We[k * D + c];
    const float bec = be[c];

    // node range: wave-pair owns nodes whose row_start falls in [lo_t, hi_t)
    int lo_t = min(rid * epw, N_EDGES);
    int hi_t = min((rid + 1) * epw, N_EDGES);
    int n_lo, n_hi;
    { int a = 0, b = N_NODES;
      while (a < b) { int m = (a + b) >> 1; if (row_start[m] < lo_t) a = m + 1; else b = m; }
      n_lo = a; }
    if (rid == nranges - 1) {
        n_hi = N_NODES;  // last range sweeps trailing (incl. degree-0) nodes
    } else {
        int a = 0, b = N_NODES;
        while (a < b) { int m = (a + b) >> 1; if (row_start[m] < hi_t) a = m + 1; else b = m; }
        n_hi = a;
    }

    for (int n = n_lo; n < n_hi; ++n) {
        float acc = x[(size_t)n * D + c];        // (1+eps)*x, eps=0
        const int ebeg = row_start[n], eend = row_start[n + 1];
        for (int e = ebeg; e < eend; ++e) {
            const int pe = permN ? permN[e] : e;
            const int sn = srcA[pe];
            const float xs = x[(size_t)sn * D + c];
            const float4* __restrict__ ar = (const float4*)&eaA[(size_t)pe * ED];
            float s0 = 0.f, s1 = 0.f, s2 = 0.f, s3 = 0.f;
            #pragma unroll
            for (int q = 0; q < 4; ++q) {
                float4 v0 = ar[q * 4 + 0], v1 = ar[q * 4 + 1];
                float4 v2 = ar[q * 4 + 2], v3 = ar[q * 4 + 3];
                s0 = fmaf(v0.x, wk[q * 16 +  0], s0); s1 = fmaf(v0.y, wk[q * 16 +  1], s1);
                s2 = fmaf(v0.z, wk[q * 16 +  2], s2); s3 = fmaf(v0.w, wk[q * 16 +  3], s3);
                s0 = fmaf(v1.x, wk[q * 16 +  4], s0); s1 = fmaf(v1.y, wk[q * 16 +  5], s1);
                s2 = fmaf(v1.z, wk[q * 16 +  6], s2); s3 = fmaf(v1.w, wk[q * 16 +  7], s3);
                s0 = fmaf(v2.x, wk[q * 16 +  8], s0); s1 = fmaf(v2.y, wk[q * 16 +  9], s1);
                s2 = fmaf(v2.z, wk[q * 16 + 10], s2); s3 = fmaf(v2.w, wk[q * 16 + 11], s3);
                s0 = fmaf(v3.x, wk[q * 16 + 12], s0); s1 = fmaf(v3.y, wk[q * 16 + 13], s1);
                s2 = fmaf(v3.z, wk[q * 16 + 14], s2); s3 = fmaf(v3.w, wk[q * 16 + 15], s3);
            }
            acc += fmaxf(xs + ((s0 + s1) + (s2 + s3)) + bec, 0.f);
        }
        hpre[(size_t)n * D + c] = acc;
    }
}

// ---------------- MLP GEMM: out = [relu](in @ W + b) ----------------

__global__ __launch_bounds__(256, 3)
void mlp_kernel(const float* __restrict__ in,   // [N][D]
                const float* __restrict__ W,    // [D][D]
                const float* __restrict__ bias, // [D]
                float* __restrict__ out,        // [N][D]
                int do_relu)
{
    __shared__ float sWh[64][D];     // 32 KB : W[k0+kl][c]
    __shared__ float sIn[64][68];    // 17.4 KB : input tile transposed [kl][row]

    const int t  = threadIdx.x;
    const int n0 = blockIdx.x * 64;
    const int r0 = (t >> 5) * 8;
    const int c0 = (t & 31) * 4;

    float acc[8][4];
    #pragma unroll
    for (int e = 0; e < 8; ++e)
        #pragma unroll
        for (int j = 0; j < 4; ++j) acc[e][j] = 0.f;

    for (int k0 = 0; k0 < D; k0 += 64) {
        __syncthreads();
        {
            const float4* w4 = (const float4*)W;
            #pragma unroll
            for (int i = 0; i < 8; ++i) {
                int idx = t + i * 256;
                int kl = idx >> 5, c4 = idx & 31;
                *(float4*)&sWh[kl][c4 * 4] = w4[(size_t)(k0 + kl) * 32 + c4];
            }
        }
        {
            int r = t & 63, prt = t >> 6;
            int gr = n0 + r;
            #pragma unroll
            for (int q = 0; q < 4; ++q) {
                float4 v = make_float4(0.f, 0.f, 0.f, 0.f);
                if (gr < N_NODES) v = ((const float4*)&in[(size_t)gr * D])[(k0 >> 2) + prt * 4 + q];
                int kl = prt * 16 + q * 4;
                sIn[kl + 0][r] = v.x;
                sIn[kl + 1][r] = v.y;
                sIn[kl + 2][r] = v.z;
                sIn[kl + 3][r] = v.w;
            }
        }
        __syncthreads();

        #pragma unroll 8
        for (int kl = 0; kl < 64; ++kl) {
            float4 b4 = *(const float4*)&sWh[kl][c0];
            float4 a0 = *(const float4*)&sIn[kl][r0];
            float4 a1 = *(const float4*)&sIn[kl][r0 + 4];
            float av[8] = {a0.x, a0.y, a0.z, a0.w, a1.x, a1.y, a1.z, a1.w};
            float bv[4] = {b4.x, b4.y, b4.z, b4.w};
            #pragma unroll
            for (int e = 0; e < 8; ++e)
                #pragma unroll
                for (int j = 0; j < 4; ++j)
                    acc[e][j] = fmaf(av[e], bv[j], acc[e][j]);
        }
    }

    float4 bb = *(const float4*)&bias[c0];
    #pragma unroll
    for (int e = 0; e < 8; ++e) {
        int gr = n0 + r0 + e;
        if (gr < N_NODES) {
            float4 o;
            o.x = acc[e][0] + bb.x;
            o.y = acc[e][1] + bb.y;
            o.z = acc[e][2] + bb.z;
            o.w = acc[e][3] + bb.w;
            if (do_relu) {
                o.x = fmaxf(o.x, 0.f); o.y = fmaxf(o.y, 0.f);
                o.z = fmaxf(o.z, 0.f); o.w = fmaxf(o.w, 0.f);
            }
            *(float4*)&out[(size_t)gr * D + c0] = o;
        }
    }
}

// ---------------- host ----------------

extern "C" void kernel_launch(void* const* d_in, const int* in_sizes, int n_in,
                              void* d_out, int out_size, void* d_ws, size_t ws_size,
                              hipStream_t stream) {
    const float* x  = (const float*)d_in[0];
    const int*   ei = (const int*)d_in[1];
    const float* ea = (const float*)d_in[2];
    const float* We = (const float*)d_in[3];
    const float* be = (const float*)d_in[4];
    const float* W1 = (const float*)d_in[5];
    const float* b1 = (const float*)d_in[6];
    const float* W2 = (const float*)d_in[7];
    const float* b2 = (const float*)d_in[8];
    float* out = (float*)d_out;

    const int* src = ei;
    const int* dst = ei + N_EDGES;

    char* ws = (char*)d_ws;
    size_t off = 0;
    auto alloc = [&](size_t bytes) -> char* {
        char* p = ws + off;
        off = (off + bytes + 255) & ~(size_t)255;
        return p;
    };
    float* P         = (float*)alloc((size_t)N_NODES * D * sizeof(float));
    float* T         = (float*)alloc((size_t)N_NODES * D * sizeof(float));
    float* H         = (float*)alloc((size_t)N_NODES * D * sizeof(float));
    int*   perm      = (int*)alloc((size_t)N_EDGES * sizeof(int));
    int*   row_start = (int*)alloc((size_t)(N_NODES + 1) * sizeof(int));
    int*   cursor    = (int*)alloc((size_t)N_NODES * sizeof(int));
    // big reordered buffers last; fall back to indirect mode if ws too small
    int*   srcd = (int*)alloc((size_t)N_EDGES * sizeof(int));
    float* ea_d = (float*)alloc((size_t)N_EDGES * ED * sizeof(float));
    const bool direct = (off <= ws_size);
    (void)in_sizes; (void)n_in; (void)out_size;

    // build dst-sorted CSR (deterministic structure; runs every call)
    hipMemsetAsync(cursor, 0, N_NODES * sizeof(int), stream);
    hist_kernel<<<(N_EDGES + 255) / 256, 256, 0, stream>>>(dst, cursor);
    scan_kernel<<<1, 1024, 0, stream>>>(cursor, row_start);
    scatter_kernel<<<(N_EDGES + 255) / 256, 256, 0, stream>>>(dst, cursor, perm);

    const float* eaA = ea;
    const int *srcA = src, *permN = perm;
    if (direct) {
        reorder_kernel<<<(N_EDGES * 4 + 255) / 256, 256, 0, stream>>>(
            (const float4*)ea, perm, src, (float4*)ea_d, srcd);
        eaA = ea_d; srcA = srcd; permN = nullptr;
    }

    // 4096 waves = exactly 4 waves/SIMD residency; 2 waves (col-halves) per range
    const int nwaves  = 4096;
    const int eblocks = nwaves / 4;                        // 256 threads = 4 waves
    const int nranges = nwaves / 2;                        // 2048
    const int epw     = (N_EDGES + nranges - 1) / nranges; // 391
    const int mgrid   = (N_NODES + 63) / 64;               // 782

    const float* X = x;
    for (int l = 0; l < NLAYERS; ++l) {
        edge_agg_kernel<<<eblocks, 256, 0, stream>>>(X, eaA, srcA, permN, row_start,
            We + (size_t)l * ED * D, be + (size_t)l * D, P, nwaves, epw);
        mlp_kernel<<<mgrid, 256, 0, stream>>>(P, W1 + (size_t)l * D * D, b1 + (size_t)l * D, T, 1);
        float* ob = (l < NLAYERS - 1) ? H : out;
        mlp_kernel<<<mgrid, 256, 0, stream>>>(T, W2 + (size_t)l * D * D, b2 + (size_t)l * D, ob,
                                              (l < NLAYERS - 1) ? 1 : 0);
        X = H;
    }
}